// Round 1
// baseline (979.164 us; speedup 1.0000x reference)
//
#include <hip/hip_runtime.h>
#include <hip/hip_bf16.h>

typedef __attribute__((ext_vector_type(8))) short short8;
typedef __attribute__((ext_vector_type(4))) short short4_t;
typedef __attribute__((ext_vector_type(4))) float floatx4;

__device__ __forceinline__ unsigned short f2bf(float f){
  unsigned int u = __float_as_uint(f);
  u += 0x7FFF + ((u >> 16) & 1);           // RNE
  return (unsigned short)(u >> 16);
}
__device__ __forceinline__ float bf2f(unsigned short h){
  return __uint_as_float(((unsigned int)h) << 16);
}
__device__ __forceinline__ float lrelu(float x){ return x > 0.f ? x : 0.2f * x; }
__device__ __forceinline__ float eluf(float x){ return x > 0.f ? x : (__expf(x) - 1.f); }

// ---------------- sort-by-dst (counting sort) ----------------

__global__ __launch_bounds__(256) void hist_k(const int* __restrict__ ei, int E, int N,
                                              int* __restrict__ counts){
  int tot = E + N;
  for (int i = blockIdx.x * blockDim.x + threadIdx.x; i < tot; i += gridDim.x * blockDim.x){
    int dst = (i < E) ? ei[E + i] : (i - E);
    atomicAdd(&counts[dst], 1);
  }
}

__global__ __launch_bounds__(1024) void scan_k(const int* __restrict__ counts,
                                               int* __restrict__ row_ptr,
                                               int* __restrict__ cursor, int n, int per){
  __shared__ int sdata[1024];
  int t = threadIdx.x;
  int base = t * per;
  int s = 0;
  for (int i = 0; i < per; i++){ int idx = base + i; if (idx < n) s += counts[idx]; }
  sdata[t] = s;
  __syncthreads();
  for (int off = 1; off < 1024; off <<= 1){
    int v = 0;
    if (t >= off) v = sdata[t - off];
    __syncthreads();
    if (t >= off) sdata[t] += v;
    __syncthreads();
  }
  int run = (t == 0) ? 0 : sdata[t - 1];
  for (int i = 0; i < per; i++){
    int idx = base + i;
    if (idx < n){ row_ptr[idx] = run; cursor[idx] = run; run += counts[idx]; }
  }
  if (t == 1023) row_ptr[n] = run;
}

__global__ __launch_bounds__(256) void scatter_k(const int* __restrict__ ei, int E, int N,
                                                 int* __restrict__ cursor,
                                                 int* __restrict__ sorted_src){
  int tot = E + N;
  for (int i = blockIdx.x * blockDim.x + threadIdx.x; i < tot; i += gridDim.x * blockDim.x){
    int dst, src;
    if (i < E){ dst = ei[E + i]; src = ei[i]; }
    else      { dst = i - E;     src = i - E; }
    int pos = atomicAdd(&cursor[dst], 1);
    sorted_src[pos] = src;
  }
}

// ---------------- conv1 tables: T1 = emb@W1 [5,256], alpha tables [5,4] ----------------

__global__ __launch_bounds__(256) void table1_k(const float* __restrict__ emb,
                                                const float* __restrict__ W1,
                                                const float* __restrict__ a1s,
                                                const float* __restrict__ a1d,
                                                float* __restrict__ T1,
                                                float* __restrict__ as_tab,
                                                float* __restrict__ ad_tab){
  __shared__ float t_lds[1280];
  int tid = threadIdx.x;
  for (int i = tid; i < 1280; i += 256){
    int r = i >> 8, c = i & 255;
    float s = 0.f;
    for (int k = 0; k < 64; k++) s += emb[r * 64 + k] * W1[k * 256 + c];
    t_lds[i] = s;
    T1[i] = s;
  }
  __syncthreads();
  if (tid < 20){
    int r = tid >> 2, hh = tid & 3;
    float ss = 0.f, sd = 0.f;
    for (int c = 0; c < 64; c++){
      float f = t_lds[r * 256 + hh * 64 + c];
      ss += f * a1s[hh * 64 + c];
      sd += f * a1d[hh * 64 + c];
    }
    as_tab[tid] = ss;
    ad_tab[tid] = sd;
  }
}

// ---------------- pack W^T to bf16: Wp[n*K+k] = W[k*Nc+n] ----------------

__global__ __launch_bounds__(256) void pack_k(const float* __restrict__ W,
                                              unsigned short* __restrict__ Wp, int K, int Nc){
  int idx = blockIdx.x * 256 + threadIdx.x;
  if (idx < K * Nc){
    int k = idx / Nc, nn = idx - k * Nc;
    Wp[nn * K + k] = f2bf(W[idx]);
  }
}

// ---------------- MFMA GEMM: C[M,Nc] = A[M,256] @ W, A bf16, Wp = W^T bf16 ----------------
// block 256 = 4 waves; tile 64 rows x 64 cols; wave w -> rows [tile+16w,+16)
__global__ __launch_bounds__(256) void gemm_k(const unsigned short* __restrict__ A,
                                              const unsigned short* __restrict__ Wp,
                                              unsigned short* __restrict__ C, int Nc){
  int tid = threadIdx.x;
  int w = tid >> 6, l = tid & 63;
  int m_base = blockIdx.x * 64 + w * 16;
  int n_base = blockIdx.y * 64;
  int r16 = l & 15;
  int quad = l >> 4;
  const short8* Ap = (const short8*)(A + (size_t)(m_base + r16) * 256 + quad * 8);
  floatx4 acc[4];
  #pragma unroll
  for (int c = 0; c < 4; c++){ floatx4 z = {0.f, 0.f, 0.f, 0.f}; acc[c] = z; }
  #pragma unroll
  for (int s = 0; s < 8; s++){
    short8 a = Ap[s * 4];
    #pragma unroll
    for (int c = 0; c < 4; c++){
      short8 b = *(const short8*)(Wp + (size_t)(n_base + c * 16 + r16) * 256 + s * 32 + quad * 8);
      acc[c] = __builtin_amdgcn_mfma_f32_16x16x32_bf16(a, b, acc[c], 0, 0, 0);
    }
  }
  #pragma unroll
  for (int c = 0; c < 4; c++){
    #pragma unroll
    for (int r = 0; r < 4; r++){
      int row = m_base + quad * 4 + r;
      int col = n_base + c * 16 + r16;
      C[(size_t)row * Nc + col] = f2bf(acc[c][r]);
    }
  }
}

// ---------------- alpha for H=4: alpha_s/d[N,4] from h[N,256] bf16 ----------------

__global__ __launch_bounds__(256) void alpha4_k(const unsigned short* __restrict__ hb,
                                                const float* __restrict__ a_src,
                                                const float* __restrict__ a_dst,
                                                float* __restrict__ as_arr,
                                                float* __restrict__ ad_arr){
  __shared__ float s_lds[256], d_lds[256];
  int tid = threadIdx.x;
  s_lds[tid] = a_src[tid];
  d_lds[tid] = a_dst[tid];
  __syncthreads();
  int node = blockIdx.x * 16 + (tid >> 4);
  int q = tid & 15;
  int head = q >> 2;
  const short8* p = (const short8*)(hb + (size_t)node * 256 + q * 16);
  float ss = 0.f, sd = 0.f;
  #pragma unroll
  for (int b = 0; b < 2; b++){
    short8 v = p[b];
    #pragma unroll
    for (int j = 0; j < 8; j++){
      int cih = ((q & 3) * 16) + b * 8 + j;
      float f = bf2f((unsigned short)v[j]);
      ss += f * s_lds[head * 64 + cih];
      sd += f * d_lds[head * 64 + cih];
    }
  }
  ss += __shfl_xor(ss, 1, 64); ss += __shfl_xor(ss, 2, 64);
  sd += __shfl_xor(sd, 1, 64); sd += __shfl_xor(sd, 2, 64);
  if ((q & 3) == 0){ as_arr[node * 4 + head] = ss; ad_arr[node * 4 + head] = sd; }
}

// ---------------- alpha for H=1: alpha_s/d[N] from h[N,64] bf16 ----------------

__global__ __launch_bounds__(256) void alpha1_k(const unsigned short* __restrict__ hb,
                                                const float* __restrict__ a_src,
                                                const float* __restrict__ a_dst,
                                                float* __restrict__ as_arr,
                                                float* __restrict__ ad_arr){
  __shared__ float s_lds[64], d_lds[64];
  int tid = threadIdx.x;
  if (tid < 64){ s_lds[tid] = a_src[tid]; d_lds[tid] = a_dst[tid]; }
  __syncthreads();
  int node = blockIdx.x * 16 + (tid >> 4);
  int q = tid & 15;
  short4_t v = *(const short4_t*)(hb + (size_t)node * 64 + q * 4);
  float ss = 0.f, sd = 0.f;
  #pragma unroll
  for (int j = 0; j < 4; j++){
    float f = bf2f((unsigned short)v[j]);
    ss += f * s_lds[q * 4 + j];
    sd += f * d_lds[q * 4 + j];
  }
  ss += __shfl_xor(ss, 1, 64); ss += __shfl_xor(ss, 2, 64);
  ss += __shfl_xor(ss, 4, 64); ss += __shfl_xor(ss, 8, 64);
  sd += __shfl_xor(sd, 1, 64); sd += __shfl_xor(sd, 2, 64);
  sd += __shfl_xor(sd, 4, 64); sd += __shfl_xor(sd, 8, 64);
  if (q == 0){ as_arr[node] = ss; ad_arr[node] = sd; }
}

// ---------------- conv1 aggregation (table-based h1), fused softmax, +b1, ELU ----------------
// one wave per dst; half-wave (32 lanes) per edge; lane covers 8 channels
__global__ __launch_bounds__(256) void agg1_k(const int* __restrict__ x,
                                              const float* __restrict__ T1,
                                              const float* __restrict__ as_tab,
                                              const float* __restrict__ ad_tab,
                                              const int* __restrict__ row_ptr,
                                              const int* __restrict__ sorted_src,
                                              const float* __restrict__ bias,
                                              unsigned short* __restrict__ outb){
  __shared__ float t_lds[1280];
  __shared__ float as_lds[20], ad_lds[20], b_lds[256];
  int tid = threadIdx.x;
  for (int i = tid; i < 1280; i += 256) t_lds[i] = T1[i];
  if (tid < 20){ as_lds[tid] = as_tab[tid]; ad_lds[tid] = ad_tab[tid]; }
  b_lds[tid] = bias[tid];
  __syncthreads();
  int w = tid >> 6, l = tid & 63;
  int d = blockIdx.x * 4 + w;
  int hl = l & 31, half = l >> 5;
  int head = hl >> 3;
  int start = row_ptr[d], end = row_ptr[d + 1];
  float a_d = ad_lds[x[d] * 4 + head];
  float acc[8] = {0.f,0.f,0.f,0.f,0.f,0.f,0.f,0.f};
  float den = 0.f;
  for (int e = start + half; e < end; e += 2){
    int s = sorted_src[e];
    int xs = x[s];
    float wg = __expf(lrelu(as_lds[xs * 4 + head] + a_d));
    den += wg;
    const float* row = &t_lds[xs * 256 + hl * 8];
    #pragma unroll
    for (int j = 0; j < 8; j++) acc[j] += wg * row[j];
  }
  #pragma unroll
  for (int j = 0; j < 8; j++) acc[j] += __shfl_xor(acc[j], 32, 64);
  den += __shfl_xor(den, 32, 64);
  if (half == 0){
    float inv = 1.f / (den + 1e-16f);
    short8 ov;
    #pragma unroll
    for (int j = 0; j < 8; j++){
      float v = eluf(acc[j] * inv + b_lds[hl * 8 + j]);
      ov[j] = (short)f2bf(v);
    }
    *(short8*)(outb + (size_t)d * 256 + hl * 8) = ov;
  }
}

// ---------------- conv2 aggregation (h[N,256] bf16), fused softmax, +b2, ELU ----------------

__global__ __launch_bounds__(256) void agg4_k(const unsigned short* __restrict__ hb,
                                              const float* __restrict__ as_arr,
                                              const float* __restrict__ ad_arr,
                                              const int* __restrict__ row_ptr,
                                              const int* __restrict__ sorted_src,
                                              const float* __restrict__ bias,
                                              unsigned short* __restrict__ outb){
  __shared__ float b_lds[256];
  int tid = threadIdx.x;
  b_lds[tid] = bias[tid];
  __syncthreads();
  int w = tid >> 6, l = tid & 63;
  int d = blockIdx.x * 4 + w;
  int hl = l & 31, half = l >> 5;
  int head = hl >> 3;
  int start = row_ptr[d], end = row_ptr[d + 1];
  float a_d = ad_arr[d * 4 + head];
  float acc[8] = {0.f,0.f,0.f,0.f,0.f,0.f,0.f,0.f};
  float den = 0.f;
  for (int e = start + half; e < end; e += 2){
    int s = sorted_src[e];
    float wg = __expf(lrelu(as_arr[s * 4 + head] + a_d));
    den += wg;
    short8 v = *(const short8*)(hb + (size_t)s * 256 + hl * 8);
    #pragma unroll
    for (int j = 0; j < 8; j++) acc[j] += wg * bf2f((unsigned short)v[j]);
  }
  #pragma unroll
  for (int j = 0; j < 8; j++) acc[j] += __shfl_xor(acc[j], 32, 64);
  den += __shfl_xor(den, 32, 64);
  if (half == 0){
    float inv = 1.f / (den + 1e-16f);
    short8 ov;
    #pragma unroll
    for (int j = 0; j < 8; j++){
      float v = eluf(acc[j] * inv + b_lds[hl * 8 + j]);
      ov[j] = (short)f2bf(v);
    }
    *(short8*)(outb + (size_t)d * 256 + hl * 8) = ov;
  }
}

// ---------------- conv3 aggregation (h[N,64] bf16, H=1), +b3, ELU ----------------
// one wave per dst; quarter-wave (16 lanes) per edge; lane covers 4 channels
__global__ __launch_bounds__(256) void agg3_k(const unsigned short* __restrict__ hb,
                                              const float* __restrict__ as_arr,
                                              const float* __restrict__ ad_arr,
                                              const int* __restrict__ row_ptr,
                                              const int* __restrict__ sorted_src,
                                              const float* __restrict__ bias,
                                              unsigned short* __restrict__ outb){
  __shared__ float b_lds[64];
  int tid = threadIdx.x;
  if (tid < 64) b_lds[tid] = bias[tid];
  __syncthreads();
  int w = tid >> 6, l = tid & 63;
  int d = blockIdx.x * 4 + w;
  int q = l & 15, grp = l >> 4;
  int start = row_ptr[d], end = row_ptr[d + 1];
  float a_d = ad_arr[d];
  float acc[4] = {0.f,0.f,0.f,0.f};
  float den = 0.f;
  for (int e = start + grp; e < end; e += 4){
    int s = sorted_src[e];
    float wg = __expf(lrelu(as_arr[s] + a_d));
    den += wg;
    short4_t v = *(const short4_t*)(hb + (size_t)s * 64 + q * 4);
    #pragma unroll
    for (int j = 0; j < 4; j++) acc[j] += wg * bf2f((unsigned short)v[j]);
  }
  #pragma unroll
  for (int j = 0; j < 4; j++){
    acc[j] += __shfl_xor(acc[j], 16, 64);
    acc[j] += __shfl_xor(acc[j], 32, 64);
  }
  den += __shfl_xor(den, 16, 64);
  den += __shfl_xor(den, 32, 64);
  if (l < 16){
    float inv = 1.f / (den + 1e-16f);
    short4_t ov;
    #pragma unroll
    for (int j = 0; j < 4; j++){
      float v = eluf(acc[j] * inv + b_lds[q * 4 + j]);
      ov[j] = (short)f2bf(v);
    }
    *(short4_t*)(outb + (size_t)d * 64 + q * 4) = ov;
  }
}

// ---------------- final FC: out[N,5] = h[N,64] @ fc_w + fc_b ----------------

__global__ __launch_bounds__(256) void fc_k(const unsigned short* __restrict__ hb,
                                            const float* __restrict__ fcw,
                                            const float* __restrict__ fcb,
                                            float* __restrict__ out){
  __shared__ float w_lds[320];
  __shared__ float b_lds[5];
  int tid = threadIdx.x;
  for (int i = tid; i < 320; i += 256) w_lds[i] = fcw[i];
  if (tid < 5) b_lds[tid] = fcb[tid];
  __syncthreads();
  int n = blockIdx.x * 256 + tid;
  const short8* p = (const short8*)(hb + (size_t)n * 64);
  float acc[5];
  #pragma unroll
  for (int j = 0; j < 5; j++) acc[j] = b_lds[j];
  #pragma unroll
  for (int b = 0; b < 8; b++){
    short8 v = p[b];
    #pragma unroll
    for (int j8 = 0; j8 < 8; j8++){
      float f = bf2f((unsigned short)v[j8]);
      int k = b * 8 + j8;
      #pragma unroll
      for (int j = 0; j < 5; j++) acc[j] += f * w_lds[k * 5 + j];
    }
  }
  #pragma unroll
  for (int j = 0; j < 5; j++) out[(size_t)n * 5 + j] = acc[j];
}

// ---------------- host launch ----------------

extern "C" void kernel_launch(void* const* d_in, const int* in_sizes, int n_in,
                              void* d_out, int out_size, void* d_ws, size_t ws_size,
                              hipStream_t stream){
  const int*   x    = (const int*)d_in[0];
  const int*   ei   = (const int*)d_in[1];
  const float* emb  = (const float*)d_in[2];
  const float* W1   = (const float*)d_in[3];
  const float* a1s  = (const float*)d_in[4];
  const float* a1d  = (const float*)d_in[5];
  const float* b1   = (const float*)d_in[6];
  const float* W2   = (const float*)d_in[7];
  const float* a2s  = (const float*)d_in[8];
  const float* a2d  = (const float*)d_in[9];
  const float* b2   = (const float*)d_in[10];
  const float* W3   = (const float*)d_in[11];
  const float* a3s  = (const float*)d_in[12];
  const float* a3d  = (const float*)d_in[13];
  const float* b3   = (const float*)d_in[14];
  const float* fcw  = (const float*)d_in[15];
  const float* fcb  = (const float*)d_in[16];
  float* out = (float*)d_out;

  const int N = in_sizes[0];
  const int E = in_sizes[1] / 2;
  const int Etot = E + N;

  // workspace partition (256B aligned)
  char* base = (char*)d_ws;
  size_t off = 0;
  auto alloc = [&](size_t bytes) -> void* {
    void* p = base + off;
    off += (bytes + 255) & ~(size_t)255;
    return p;
  };
  unsigned short* bufA    = (unsigned short*)alloc((size_t)N * 256 * 2);
  unsigned short* bufB    = (unsigned short*)alloc((size_t)N * 256 * 2);
  float* alpha_s          = (float*)alloc((size_t)N * 4 * 4);
  float* alpha_d          = (float*)alloc((size_t)N * 4 * 4);
  int* counts             = (int*)alloc((size_t)N * 4);
  int* row_ptr            = (int*)alloc((size_t)(N + 1) * 4);
  int* cursor             = (int*)alloc((size_t)N * 4);
  int* sorted_src         = (int*)alloc((size_t)Etot * 4);
  float* T1               = (float*)alloc(5 * 256 * 4);
  float* as_tab           = (float*)alloc(20 * 4);
  float* ad_tab           = (float*)alloc(20 * 4);
  unsigned short* Wp2     = (unsigned short*)alloc(256 * 256 * 2);
  unsigned short* Wp3     = (unsigned short*)alloc(64 * 256 * 2);

  // ---- build CSR by dst (shared by all 3 convs) ----
  hipMemsetAsync(counts, 0, (size_t)N * 4, stream);
  hist_k<<<1024, 256, 0, stream>>>(ei, E, N, counts);
  scan_k<<<1, 1024, 0, stream>>>(counts, row_ptr, cursor, N, (N + 1023) / 1024);
  scatter_k<<<1024, 256, 0, stream>>>(ei, E, N, cursor, sorted_src);

  // ---- prep: conv1 tables, packed bf16 weights ----
  table1_k<<<1, 256, 0, stream>>>(emb, W1, a1s, a1d, T1, as_tab, ad_tab);
  pack_k<<<(256 * 256 + 255) / 256, 256, 0, stream>>>(W2, Wp2, 256, 256);
  pack_k<<<(256 * 64 + 255) / 256, 256, 0, stream>>>(W3, Wp3, 256, 64);

  // ---- conv1: table-gather aggregation -> bufB [N,256] bf16 ----
  agg1_k<<<N / 4, 256, 0, stream>>>(x, T1, as_tab, ad_tab, row_ptr, sorted_src, b1, bufB);

  // ---- conv2 ----
  gemm_k<<<dim3(N / 64, 4), 256, 0, stream>>>(bufB, Wp2, bufA, 256);
  alpha4_k<<<N / 16, 256, 0, stream>>>(bufA, a2s, a2d, alpha_s, alpha_d);
  agg4_k<<<N / 4, 256, 0, stream>>>(bufA, alpha_s, alpha_d, row_ptr, sorted_src, b2, bufB);

  // ---- conv3 ----
  gemm_k<<<dim3(N / 64, 1), 256, 0, stream>>>(bufB, Wp3, bufA, 64);
  alpha1_k<<<N / 16, 256, 0, stream>>>(bufA, a3s, a3d, alpha_s, alpha_d);
  agg3_k<<<N / 4, 256, 0, stream>>>(bufA, alpha_s, alpha_d, row_ptr, sorted_src, b3, bufB);

  // ---- final FC -> d_out [N,5] f32 ----
  fc_k<<<N / 256, 256, 0, stream>>>(bufB, fcw, fcb, out);
}

// Round 2
// 696.508 us; speedup vs baseline: 1.4058x; 1.4058x over previous
//
#include <hip/hip_runtime.h>
#include <hip/hip_bf16.h>

typedef __attribute__((ext_vector_type(8))) short short8;
typedef __attribute__((ext_vector_type(4))) short short4_t;
typedef __attribute__((ext_vector_type(4))) float floatx4;

__device__ __forceinline__ unsigned short f2bf(float f){
  unsigned int u = __float_as_uint(f);
  u += 0x7FFF + ((u >> 16) & 1);           // RNE
  return (unsigned short)(u >> 16);
}
__device__ __forceinline__ float bf2f(unsigned short h){
  return __uint_as_float(((unsigned int)h) << 16);
}
__device__ __forceinline__ float lrelu(float x){ return x > 0.f ? x : 0.2f * x; }
__device__ __forceinline__ float eluf(float x){ return x > 0.f ? x : (__expf(x) - 1.f); }

// ---------------- sort-by-dst (counting sort) ----------------

__global__ __launch_bounds__(256) void hist_k(const int* __restrict__ ei, int E, int N,
                                              int* __restrict__ counts){
  int tot = E + N;
  for (int i = blockIdx.x * blockDim.x + threadIdx.x; i < tot; i += gridDim.x * blockDim.x){
    int dst = (i < E) ? ei[E + i] : (i - E);
    atomicAdd(&counts[dst], 1);
  }
}

// ---- 3-phase device-wide exclusive scan of counts[N] -> row_ptr/cursor ----
// phase 1: each block scans its 1024-chunk in LDS, writes per-block exclusive
// prefix into row_ptr and block total into bsum
__global__ __launch_bounds__(1024) void scan_blk_k(const int* __restrict__ counts,
                                                   int* __restrict__ row_ptr,
                                                   int* __restrict__ bsum, int n){
  __shared__ int sdata[1024];
  int t = threadIdx.x;
  int idx = blockIdx.x * 1024 + t;
  int v = (idx < n) ? counts[idx] : 0;
  sdata[t] = v;
  __syncthreads();
  #pragma unroll
  for (int off = 1; off < 1024; off <<= 1){
    int u = (t >= off) ? sdata[t - off] : 0;
    __syncthreads();
    sdata[t] += u;
    __syncthreads();
  }
  if (idx < n) row_ptr[idx] = sdata[t] - v;         // exclusive within block
  if (t == 1023) bsum[blockIdx.x] = sdata[1023];    // block total
}

// phase 2: single block scans the nb block totals (exclusive); bsum[nb] = grand total
__global__ __launch_bounds__(1024) void scan_top_k(int* __restrict__ bsum, int nb){
  __shared__ int sdata[1024];
  int t = threadIdx.x;
  int v = (t < nb) ? bsum[t] : 0;
  sdata[t] = v;
  __syncthreads();
  #pragma unroll
  for (int off = 1; off < 1024; off <<= 1){
    int u = (t >= off) ? sdata[t - off] : 0;
    __syncthreads();
    sdata[t] += u;
    __syncthreads();
  }
  if (t < nb) bsum[t] = sdata[t] - v;               // exclusive
  if (t == nb - 1) bsum[nb] = sdata[t];             // grand total
}

// phase 3: add block offsets; emit row_ptr, cursor, row_ptr[n]
__global__ __launch_bounds__(1024) void scan_add_k(const int* __restrict__ bsum,
                                                   int* __restrict__ row_ptr,
                                                   int* __restrict__ cursor, int n, int nb){
  int idx = blockIdx.x * 1024 + threadIdx.x;
  if (idx < n){
    int v = row_ptr[idx] + bsum[blockIdx.x];
    row_ptr[idx] = v;
    cursor[idx] = v;
  }
  if (idx == 0) row_ptr[n] = bsum[nb];
}

__global__ __launch_bounds__(256) void scatter_k(const int* __restrict__ ei, int E, int N,
                                                 int* __restrict__ cursor,
                                                 int* __restrict__ sorted_src){
  int tot = E + N;
  for (int i = blockIdx.x * blockDim.x + threadIdx.x; i < tot; i += gridDim.x * blockDim.x){
    int dst, src;
    if (i < E){ dst = ei[E + i]; src = ei[i]; }
    else      { dst = i - E;     src = i - E; }
    int pos = atomicAdd(&cursor[dst], 1);
    sorted_src[pos] = src;
  }
}

// ---------------- conv1 tables: T1 = emb@W1 [5,256], alpha tables [5,4] ----------------

__global__ __launch_bounds__(256) void table1_k(const float* __restrict__ emb,
                                                const float* __restrict__ W1,
                                                const float* __restrict__ a1s,
                                                const float* __restrict__ a1d,
                                                float* __restrict__ T1,
                                                float* __restrict__ as_tab,
                                                float* __restrict__ ad_tab){
  __shared__ float t_lds[1280];
  int tid = threadIdx.x;
  for (int i = tid; i < 1280; i += 256){
    int r = i >> 8, c = i & 255;
    float s = 0.f;
    for (int k = 0; k < 64; k++) s += emb[r * 64 + k] * W1[k * 256 + c];
    t_lds[i] = s;
    T1[i] = s;
  }
  __syncthreads();
  if (tid < 20){
    int r = tid >> 2, hh = tid & 3;
    float ss = 0.f, sd = 0.f;
    for (int c = 0; c < 64; c++){
      float f = t_lds[r * 256 + hh * 64 + c];
      ss += f * a1s[hh * 64 + c];
      sd += f * a1d[hh * 64 + c];
    }
    as_tab[tid] = ss;
    ad_tab[tid] = sd;
  }
}

// ---------------- pack W^T to bf16: Wp[n*K+k] = W[k*Nc+n] ----------------

__global__ __launch_bounds__(256) void pack_k(const float* __restrict__ W,
                                              unsigned short* __restrict__ Wp, int K, int Nc){
  int idx = blockIdx.x * 256 + threadIdx.x;
  if (idx < K * Nc){
    int k = idx / Nc, nn = idx - k * Nc;
    Wp[nn * K + k] = f2bf(W[idx]);
  }
}

// ---------------- MFMA GEMM: C[M,Nc] = A[M,256] @ W, A bf16, Wp = W^T bf16 ----------------
// block 256 = 4 waves; tile 64 rows x 64 cols; wave w -> rows [tile+16w,+16)
__global__ __launch_bounds__(256) void gemm_k(const unsigned short* __restrict__ A,
                                              const unsigned short* __restrict__ Wp,
                                              unsigned short* __restrict__ C, int Nc){
  int tid = threadIdx.x;
  int w = tid >> 6, l = tid & 63;
  int m_base = blockIdx.x * 64 + w * 16;
  int n_base = blockIdx.y * 64;
  int r16 = l & 15;
  int quad = l >> 4;
  const short8* Ap = (const short8*)(A + (size_t)(m_base + r16) * 256 + quad * 8);
  floatx4 acc[4];
  #pragma unroll
  for (int c = 0; c < 4; c++){ floatx4 z = {0.f, 0.f, 0.f, 0.f}; acc[c] = z; }
  #pragma unroll
  for (int s = 0; s < 8; s++){
    short8 a = Ap[s * 4];
    #pragma unroll
    for (int c = 0; c < 4; c++){
      short8 b = *(const short8*)(Wp + (size_t)(n_base + c * 16 + r16) * 256 + s * 32 + quad * 8);
      acc[c] = __builtin_amdgcn_mfma_f32_16x16x32_bf16(a, b, acc[c], 0, 0, 0);
    }
  }
  #pragma unroll
  for (int c = 0; c < 4; c++){
    #pragma unroll
    for (int r = 0; r < 4; r++){
      int row = m_base + quad * 4 + r;
      int col = n_base + c * 16 + r16;
      C[(size_t)row * Nc + col] = f2bf(acc[c][r]);
    }
  }
}

// ---------------- alpha for H=4: alpha_s/d[N,4] from h[N,256] bf16 ----------------

__global__ __launch_bounds__(256) void alpha4_k(const unsigned short* __restrict__ hb,
                                                const float* __restrict__ a_src,
                                                const float* __restrict__ a_dst,
                                                float* __restrict__ as_arr,
                                                float* __restrict__ ad_arr){
  __shared__ float s_lds[256], d_lds[256];
  int tid = threadIdx.x;
  s_lds[tid] = a_src[tid];
  d_lds[tid] = a_dst[tid];
  __syncthreads();
  int node = blockIdx.x * 16 + (tid >> 4);
  int q = tid & 15;
  int head = q >> 2;
  const short8* p = (const short8*)(hb + (size_t)node * 256 + q * 16);
  float ss = 0.f, sd = 0.f;
  #pragma unroll
  for (int b = 0; b < 2; b++){
    short8 v = p[b];
    #pragma unroll
    for (int j = 0; j < 8; j++){
      int cih = ((q & 3) * 16) + b * 8 + j;
      float f = bf2f((unsigned short)v[j]);
      ss += f * s_lds[head * 64 + cih];
      sd += f * d_lds[head * 64 + cih];
    }
  }
  ss += __shfl_xor(ss, 1, 64); ss += __shfl_xor(ss, 2, 64);
  sd += __shfl_xor(sd, 1, 64); sd += __shfl_xor(sd, 2, 64);
  if ((q & 3) == 0){ as_arr[node * 4 + head] = ss; ad_arr[node * 4 + head] = sd; }
}

// ---------------- alpha for H=1: alpha_s/d[N] from h[N,64] bf16 ----------------

__global__ __launch_bounds__(256) void alpha1_k(const unsigned short* __restrict__ hb,
                                                const float* __restrict__ a_src,
                                                const float* __restrict__ a_dst,
                                                float* __restrict__ as_arr,
                                                float* __restrict__ ad_arr){
  __shared__ float s_lds[64], d_lds[64];
  int tid = threadIdx.x;
  if (tid < 64){ s_lds[tid] = a_src[tid]; d_lds[tid] = a_dst[tid]; }
  __syncthreads();
  int node = blockIdx.x * 16 + (tid >> 4);
  int q = tid & 15;
  short4_t v = *(const short4_t*)(hb + (size_t)node * 64 + q * 4);
  float ss = 0.f, sd = 0.f;
  #pragma unroll
  for (int j = 0; j < 4; j++){
    float f = bf2f((unsigned short)v[j]);
    ss += f * s_lds[q * 4 + j];
    sd += f * d_lds[q * 4 + j];
  }
  ss += __shfl_xor(ss, 1, 64); ss += __shfl_xor(ss, 2, 64);
  ss += __shfl_xor(ss, 4, 64); ss += __shfl_xor(ss, 8, 64);
  sd += __shfl_xor(sd, 1, 64); sd += __shfl_xor(sd, 2, 64);
  sd += __shfl_xor(sd, 4, 64); sd += __shfl_xor(sd, 8, 64);
  if (q == 0){ as_arr[node] = ss; ad_arr[node] = sd; }
}

// ---------------- conv1 aggregation (table-based h1), fused softmax, +b1, ELU ----------------
// one wave per dst; half-wave (32 lanes) per edge; lane covers 8 channels
__global__ __launch_bounds__(256) void agg1_k(const int* __restrict__ x,
                                              const float* __restrict__ T1,
                                              const float* __restrict__ as_tab,
                                              const float* __restrict__ ad_tab,
                                              const int* __restrict__ row_ptr,
                                              const int* __restrict__ sorted_src,
                                              const float* __restrict__ bias,
                                              unsigned short* __restrict__ outb){
  __shared__ float t_lds[1280];
  __shared__ float as_lds[20], ad_lds[20], b_lds[256];
  int tid = threadIdx.x;
  for (int i = tid; i < 1280; i += 256) t_lds[i] = T1[i];
  if (tid < 20){ as_lds[tid] = as_tab[tid]; ad_lds[tid] = ad_tab[tid]; }
  b_lds[tid] = bias[tid];
  __syncthreads();
  int w = tid >> 6, l = tid & 63;
  int d = blockIdx.x * 4 + w;
  int hl = l & 31, half = l >> 5;
  int head = hl >> 3;
  int start = row_ptr[d], end = row_ptr[d + 1];
  float a_d = ad_lds[x[d] * 4 + head];
  float acc[8] = {0.f,0.f,0.f,0.f,0.f,0.f,0.f,0.f};
  float den = 0.f;
  for (int e = start + half; e < end; e += 2){
    int s = sorted_src[e];
    int xs = x[s];
    float wg = __expf(lrelu(as_lds[xs * 4 + head] + a_d));
    den += wg;
    const float* row = &t_lds[xs * 256 + hl * 8];
    #pragma unroll
    for (int j = 0; j < 8; j++) acc[j] += wg * row[j];
  }
  #pragma unroll
  for (int j = 0; j < 8; j++) acc[j] += __shfl_xor(acc[j], 32, 64);
  den += __shfl_xor(den, 32, 64);
  if (half == 0){
    float inv = 1.f / (den + 1e-16f);
    short8 ov;
    #pragma unroll
    for (int j = 0; j < 8; j++){
      float v = eluf(acc[j] * inv + b_lds[hl * 8 + j]);
      ov[j] = (short)f2bf(v);
    }
    *(short8*)(outb + (size_t)d * 256 + hl * 8) = ov;
  }
}

// ---------------- conv2 aggregation (h[N,256] bf16), fused softmax, +b2, ELU ----------------

__global__ __launch_bounds__(256) void agg4_k(const unsigned short* __restrict__ hb,
                                              const float* __restrict__ as_arr,
                                              const float* __restrict__ ad_arr,
                                              const int* __restrict__ row_ptr,
                                              const int* __restrict__ sorted_src,
                                              const float* __restrict__ bias,
                                              unsigned short* __restrict__ outb){
  __shared__ float b_lds[256];
  int tid = threadIdx.x;
  b_lds[tid] = bias[tid];
  __syncthreads();
  int w = tid >> 6, l = tid & 63;
  int d = blockIdx.x * 4 + w;
  int hl = l & 31, half = l >> 5;
  int head = hl >> 3;
  int start = row_ptr[d], end = row_ptr[d + 1];
  float a_d = ad_arr[d * 4 + head];
  float acc[8] = {0.f,0.f,0.f,0.f,0.f,0.f,0.f,0.f};
  float den = 0.f;
  for (int e = start + half; e < end; e += 2){
    int s = sorted_src[e];
    float wg = __expf(lrelu(as_arr[s * 4 + head] + a_d));
    den += wg;
    short8 v = *(const short8*)(hb + (size_t)s * 256 + hl * 8);
    #pragma unroll
    for (int j = 0; j < 8; j++) acc[j] += wg * bf2f((unsigned short)v[j]);
  }
  #pragma unroll
  for (int j = 0; j < 8; j++) acc[j] += __shfl_xor(acc[j], 32, 64);
  den += __shfl_xor(den, 32, 64);
  if (half == 0){
    float inv = 1.f / (den + 1e-16f);
    short8 ov;
    #pragma unroll
    for (int j = 0; j < 8; j++){
      float v = eluf(acc[j] * inv + b_lds[hl * 8 + j]);
      ov[j] = (short)f2bf(v);
    }
    *(short8*)(outb + (size_t)d * 256 + hl * 8) = ov;
  }
}

// ---------------- conv3 aggregation (h[N,64] bf16, H=1), +b3, ELU ----------------
// one wave per dst; quarter-wave (16 lanes) per edge; lane covers 4 channels
__global__ __launch_bounds__(256) void agg3_k(const unsigned short* __restrict__ hb,
                                              const float* __restrict__ as_arr,
                                              const float* __restrict__ ad_arr,
                                              const int* __restrict__ row_ptr,
                                              const int* __restrict__ sorted_src,
                                              const float* __restrict__ bias,
                                              unsigned short* __restrict__ outb){
  __shared__ float b_lds[64];
  int tid = threadIdx.x;
  if (tid < 64) b_lds[tid] = bias[tid];
  __syncthreads();
  int w = tid >> 6, l = tid & 63;
  int d = blockIdx.x * 4 + w;
  int q = l & 15, grp = l >> 4;
  int start = row_ptr[d], end = row_ptr[d + 1];
  float a_d = ad_arr[d];
  float acc[4] = {0.f,0.f,0.f,0.f};
  float den = 0.f;
  for (int e = start + grp; e < end; e += 4){
    int s = sorted_src[e];
    float wg = __expf(lrelu(as_arr[s] + a_d));
    den += wg;
    short4_t v = *(const short4_t*)(hb + (size_t)s * 64 + q * 4);
    #pragma unroll
    for (int j = 0; j < 4; j++) acc[j] += wg * bf2f((unsigned short)v[j]);
  }
  #pragma unroll
  for (int j = 0; j < 4; j++){
    acc[j] += __shfl_xor(acc[j], 16, 64);
    acc[j] += __shfl_xor(acc[j], 32, 64);
  }
  den += __shfl_xor(den, 16, 64);
  den += __shfl_xor(den, 32, 64);
  if (l < 16){
    float inv = 1.f / (den + 1e-16f);
    short4_t ov;
    #pragma unroll
    for (int j = 0; j < 4; j++){
      float v = eluf(acc[j] * inv + b_lds[q * 4 + j]);
      ov[j] = (short)f2bf(v);
    }
    *(short4_t*)(outb + (size_t)d * 64 + q * 4) = ov;
  }
}

// ---------------- final FC: out[N,5] = h[N,64] @ fc_w + fc_b ----------------

__global__ __launch_bounds__(256) void fc_k(const unsigned short* __restrict__ hb,
                                            const float* __restrict__ fcw,
                                            const float* __restrict__ fcb,
                                            float* __restrict__ out){
  __shared__ float w_lds[320];
  __shared__ float b_lds[5];
  int tid = threadIdx.x;
  for (int i = tid; i < 320; i += 256) w_lds[i] = fcw[i];
  if (tid < 5) b_lds[tid] = fcb[tid];
  __syncthreads();
  int n = blockIdx.x * 256 + tid;
  const short8* p = (const short8*)(hb + (size_t)n * 64);
  float acc[5];
  #pragma unroll
  for (int j = 0; j < 5; j++) acc[j] = b_lds[j];
  #pragma unroll
  for (int b = 0; b < 8; b++){
    short8 v = p[b];
    #pragma unroll
    for (int j8 = 0; j8 < 8; j8++){
      float f = bf2f((unsigned short)v[j8]);
      int k = b * 8 + j8;
      #pragma unroll
      for (int j = 0; j < 5; j++) acc[j] += f * w_lds[k * 5 + j];
    }
  }
  #pragma unroll
  for (int j = 0; j < 5; j++) out[(size_t)n * 5 + j] = acc[j];
}

// ---------------- host launch ----------------

extern "C" void kernel_launch(void* const* d_in, const int* in_sizes, int n_in,
                              void* d_out, int out_size, void* d_ws, size_t ws_size,
                              hipStream_t stream){
  const int*   x    = (const int*)d_in[0];
  const int*   ei   = (const int*)d_in[1];
  const float* emb  = (const float*)d_in[2];
  const float* W1   = (const float*)d_in[3];
  const float* a1s  = (const float*)d_in[4];
  const float* a1d  = (const float*)d_in[5];
  const float* b1   = (const float*)d_in[6];
  const float* W2   = (const float*)d_in[7];
  const float* a2s  = (const float*)d_in[8];
  const float* a2d  = (const float*)d_in[9];
  const float* b2   = (const float*)d_in[10];
  const float* W3   = (const float*)d_in[11];
  const float* a3s  = (const float*)d_in[12];
  const float* a3d  = (const float*)d_in[13];
  const float* b3   = (const float*)d_in[14];
  const float* fcw  = (const float*)d_in[15];
  const float* fcb  = (const float*)d_in[16];
  float* out = (float*)d_out;

  const int N = in_sizes[0];
  const int E = in_sizes[1] / 2;
  const int Etot = E + N;
  const int nb = (N + 1023) / 1024;   // scan blocks

  // workspace partition (256B aligned)
  char* base = (char*)d_ws;
  size_t off = 0;
  auto alloc = [&](size_t bytes) -> void* {
    void* p = base + off;
    off += (bytes + 255) & ~(size_t)255;
    return p;
  };
  unsigned short* bufA    = (unsigned short*)alloc((size_t)N * 256 * 2);
  unsigned short* bufB    = (unsigned short*)alloc((size_t)N * 256 * 2);
  float* alpha_s          = (float*)alloc((size_t)N * 4 * 4);
  float* alpha_d          = (float*)alloc((size_t)N * 4 * 4);
  int* counts             = (int*)alloc((size_t)N * 4);
  int* row_ptr            = (int*)alloc((size_t)(N + 1) * 4);
  int* cursor             = (int*)alloc((size_t)N * 4);
  int* sorted_src         = (int*)alloc((size_t)Etot * 4);
  int* bsum               = (int*)alloc((size_t)(nb + 1) * 4);
  float* T1               = (float*)alloc(5 * 256 * 4);
  float* as_tab           = (float*)alloc(20 * 4);
  float* ad_tab           = (float*)alloc(20 * 4);
  unsigned short* Wp2     = (unsigned short*)alloc(256 * 256 * 2);
  unsigned short* Wp3     = (unsigned short*)alloc(64 * 256 * 2);

  // ---- build CSR by dst (shared by all 3 convs) ----
  hipMemsetAsync(counts, 0, (size_t)N * 4, stream);
  hist_k<<<1024, 256, 0, stream>>>(ei, E, N, counts);
  scan_blk_k<<<nb, 1024, 0, stream>>>(counts, row_ptr, bsum, N);
  scan_top_k<<<1, 1024, 0, stream>>>(bsum, nb);
  scan_add_k<<<nb, 1024, 0, stream>>>(bsum, row_ptr, cursor, N, nb);
  scatter_k<<<1024, 256, 0, stream>>>(ei, E, N, cursor, sorted_src);

  // ---- prep: conv1 tables, packed bf16 weights ----
  table1_k<<<1, 256, 0, stream>>>(emb, W1, a1s, a1d, T1, as_tab, ad_tab);
  pack_k<<<(256 * 256 + 255) / 256, 256, 0, stream>>>(W2, Wp2, 256, 256);
  pack_k<<<(256 * 64 + 255) / 256, 256, 0, stream>>>(W3, Wp3, 256, 64);

  // ---- conv1: table-gather aggregation -> bufB [N,256] bf16 ----
  agg1_k<<<N / 4, 256, 0, stream>>>(x, T1, as_tab, ad_tab, row_ptr, sorted_src, b1, bufB);

  // ---- conv2 ----
  gemm_k<<<dim3(N / 64, 4), 256, 0, stream>>>(bufB, Wp2, bufA, 256);
  alpha4_k<<<N / 16, 256, 0, stream>>>(bufA, a2s, a2d, alpha_s, alpha_d);
  agg4_k<<<N / 4, 256, 0, stream>>>(bufA, alpha_s, alpha_d, row_ptr, sorted_src, b2, bufB);

  // ---- conv3 ----
  gemm_k<<<dim3(N / 64, 1), 256, 0, stream>>>(bufB, Wp3, bufA, 64);
  alpha1_k<<<N / 16, 256, 0, stream>>>(bufA, a3s, a3d, alpha_s, alpha_d);
  agg3_k<<<N / 4, 256, 0, stream>>>(bufA, alpha_s, alpha_d, row_ptr, sorted_src, b3, bufB);

  // ---- final FC -> d_out [N,5] f32 ----
  fc_k<<<N / 256, 256, 0, stream>>>(bufB, fcw, fcb, out);
}

// Round 3
// 561.517 us; speedup vs baseline: 1.7438x; 1.2404x over previous
//
#include <hip/hip_runtime.h>
#include <hip/hip_bf16.h>

typedef __attribute__((ext_vector_type(8))) short short8;
typedef __attribute__((ext_vector_type(4))) short short4_t;
typedef __attribute__((ext_vector_type(4))) float floatx4;

__device__ __forceinline__ unsigned short f2bf(float f){
  unsigned int u = __float_as_uint(f);
  u += 0x7FFF + ((u >> 16) & 1);           // RNE
  return (unsigned short)(u >> 16);
}
__device__ __forceinline__ float bf2f(unsigned short h){
  return __uint_as_float(((unsigned int)h) << 16);
}
__device__ __forceinline__ float lrelu(float x){ return x > 0.f ? x : 0.2f * x; }
__device__ __forceinline__ float eluf(float x){ return x > 0.f ? x : (__expf(x) - 1.f); }

// async global->LDS, 16B per lane; LDS dest = base + lane*16
__device__ __forceinline__ void gload16(const unsigned short* g, unsigned short* l){
  __builtin_amdgcn_global_load_lds(
      (const __attribute__((address_space(1))) unsigned int*)(const void*)g,
      (__attribute__((address_space(3))) unsigned int*)(void*)l,
      16, 0, 0);
}

// ---------------- sort-by-dst (counting sort) ----------------

__global__ __launch_bounds__(256) void hist_k(const int* __restrict__ ei, int E, int N,
                                              int* __restrict__ counts){
  int tot = E + N;
  for (int i = blockIdx.x * blockDim.x + threadIdx.x; i < tot; i += gridDim.x * blockDim.x){
    int dst = (i < E) ? ei[E + i] : (i - E);
    atomicAdd(&counts[dst], 1);
  }
}

__global__ __launch_bounds__(1024) void scan_blk_k(const int* __restrict__ counts,
                                                   int* __restrict__ row_ptr,
                                                   int* __restrict__ bsum, int n){
  __shared__ int sdata[1024];
  int t = threadIdx.x;
  int idx = blockIdx.x * 1024 + t;
  int v = (idx < n) ? counts[idx] : 0;
  sdata[t] = v;
  __syncthreads();
  #pragma unroll
  for (int off = 1; off < 1024; off <<= 1){
    int u = (t >= off) ? sdata[t - off] : 0;
    __syncthreads();
    sdata[t] += u;
    __syncthreads();
  }
  if (idx < n) row_ptr[idx] = sdata[t] - v;
  if (t == 1023) bsum[blockIdx.x] = sdata[1023];
}

__global__ __launch_bounds__(1024) void scan_top_k(int* __restrict__ bsum, int nb){
  __shared__ int sdata[1024];
  int t = threadIdx.x;
  int v = (t < nb) ? bsum[t] : 0;
  sdata[t] = v;
  __syncthreads();
  #pragma unroll
  for (int off = 1; off < 1024; off <<= 1){
    int u = (t >= off) ? sdata[t - off] : 0;
    __syncthreads();
    sdata[t] += u;
    __syncthreads();
  }
  if (t < nb) bsum[t] = sdata[t] - v;
  if (t == nb - 1) bsum[nb] = sdata[t];
}

__global__ __launch_bounds__(1024) void scan_add_k(const int* __restrict__ bsum,
                                                   int* __restrict__ row_ptr,
                                                   int* __restrict__ cursor, int n, int nb){
  int idx = blockIdx.x * 1024 + threadIdx.x;
  if (idx < n){
    int v = row_ptr[idx] + bsum[blockIdx.x];
    row_ptr[idx] = v;
    cursor[idx] = v;
  }
  if (idx == 0) row_ptr[n] = bsum[nb];
}

__global__ __launch_bounds__(256) void scatter_k(const int* __restrict__ ei, int E, int N,
                                                 int* __restrict__ cursor,
                                                 int* __restrict__ sorted_src){
  int tot = E + N;
  for (int i = blockIdx.x * blockDim.x + threadIdx.x; i < tot; i += gridDim.x * blockDim.x){
    int dst, src;
    if (i < E){ dst = ei[E + i]; src = ei[i]; }
    else      { dst = i - E;     src = i - E; }
    int pos = atomicAdd(&cursor[dst], 1);
    sorted_src[pos] = src;
  }
}

// ---------------- conv1 tables: T1 = emb@W1 [5,256], alpha tables [5,4] ----------------

__global__ __launch_bounds__(256) void table1_k(const float* __restrict__ emb,
                                                const float* __restrict__ W1,
                                                const float* __restrict__ a1s,
                                                const float* __restrict__ a1d,
                                                float* __restrict__ T1,
                                                float* __restrict__ as_tab,
                                                float* __restrict__ ad_tab){
  __shared__ float t_lds[1280];
  int tid = threadIdx.x;
  for (int i = tid; i < 1280; i += 256){
    int r = i >> 8, c = i & 255;
    float s = 0.f;
    for (int k = 0; k < 64; k++) s += emb[r * 64 + k] * W1[k * 256 + c];
    t_lds[i] = s;
    T1[i] = s;
  }
  __syncthreads();
  if (tid < 20){
    int r = tid >> 2, hh = tid & 3;
    float ss = 0.f, sd = 0.f;
    for (int c = 0; c < 64; c++){
      float f = t_lds[r * 256 + hh * 64 + c];
      ss += f * a1s[hh * 64 + c];
      sd += f * a1d[hh * 64 + c];
    }
    as_tab[tid] = ss;
    ad_tab[tid] = sd;
  }
}

// ---------------- pack W^T to bf16: Wp[n*K+k] = W[k*Nc+n] ----------------

__global__ __launch_bounds__(256) void pack_k(const float* __restrict__ W,
                                              unsigned short* __restrict__ Wp, int K, int Nc){
  int idx = blockIdx.x * 256 + threadIdx.x;
  if (idx < K * Nc){
    int k = idx / Nc, nn = idx - k * Nc;
    Wp[nn * K + k] = f2bf(W[idx]);
  }
}

// ---------------- LDS-staged MFMA GEMM (m97 structure) ----------------
// C[M,Nc] = A[M,256] @ W ;  A bf16 row-major, Wp = W^T bf16 [Nc,256]
// block 256 thr = 4 waves in 2x2; tile 128 x BN; BK=32, K=256 (8 iters)
// wave (wr,wc): rows wr*64 + mt*16, cols wc*(BN/2) + nt*16
template<int BN>
__global__ __launch_bounds__(256) void gemm_lds_k(const unsigned short* __restrict__ A,
                                                  const unsigned short* __restrict__ Wp,
                                                  unsigned short* __restrict__ C, int Nc){
  constexpr int K = 256;
  constexpr int NT = BN / 32;               // col tiles per wave (4 or 2)
  __shared__ unsigned short Alds[128 * 32];
  __shared__ unsigned short Blds[BN * 32];
  int tid = threadIdx.x;
  int w = tid >> 6, l = tid & 63;
  int r16 = l & 15, quad = l >> 4;
  int wr = w >> 1, wc = w & 1;
  int mBase = blockIdx.x * 128;
  int nBase = blockIdx.y * BN;

  // staging: lane i -> row i>>2, 16B chunk i&3 (16 rows x 64B = 1KB per inst)
  int arow = l >> 2;
  int kcol = (l & 3) * 8;                   // shorts
  const unsigned short* gA0 = A + (size_t)(mBase + w * 32 + arow) * K + kcol;
  const unsigned short* gA1 = gA0 + (size_t)16 * K;
  unsigned short* lA0 = &Alds[(w * 32) * 32];
  unsigned short* lA1 = &Alds[(w * 32 + 16) * 32];
  const unsigned short* gB0;
  const unsigned short* gB1 = nullptr;
  unsigned short* lB0;
  unsigned short* lB1 = nullptr;
  if constexpr (BN == 128){
    gB0 = Wp + (size_t)(nBase + w * 32 + arow) * K + kcol;
    gB1 = gB0 + (size_t)16 * K;
    lB0 = &Blds[(w * 32) * 32];
    lB1 = &Blds[(w * 32 + 16) * 32];
  } else {
    gB0 = Wp + (size_t)(nBase + w * 16 + arow) * K + kcol;
    lB0 = &Blds[(w * 16) * 32];
  }

  floatx4 acc[4][NT];
  #pragma unroll
  for (int mt = 0; mt < 4; mt++)
    #pragma unroll
    for (int nt = 0; nt < NT; nt++){ floatx4 z = {0.f,0.f,0.f,0.f}; acc[mt][nt] = z; }

  for (int kt = 0; kt < 8; kt++){
    int ko = kt * 32;
    gload16(gA0 + ko, lA0);
    gload16(gA1 + ko, lA1);
    gload16(gB0 + ko, lB0);
    if constexpr (BN == 128) gload16(gB1 + ko, lB1);
    __syncthreads();
    short8 af[4], bfr[NT];
    #pragma unroll
    for (int mt = 0; mt < 4; mt++)
      af[mt] = *(const short8*)&Alds[(wr * 64 + mt * 16 + r16) * 32 + quad * 8];
    #pragma unroll
    for (int nt = 0; nt < NT; nt++)
      bfr[nt] = *(const short8*)&Blds[(wc * (BN / 2) + nt * 16 + r16) * 32 + quad * 8];
    #pragma unroll
    for (int mt = 0; mt < 4; mt++)
      #pragma unroll
      for (int nt = 0; nt < NT; nt++)
        acc[mt][nt] = __builtin_amdgcn_mfma_f32_16x16x32_bf16(af[mt], bfr[nt], acc[mt][nt], 0, 0, 0);
    __syncthreads();
  }

  // epilogue: C/D layout col=lane&15, row=quad*4+reg
  #pragma unroll
  for (int mt = 0; mt < 4; mt++){
    #pragma unroll
    for (int nt = 0; nt < NT; nt++){
      #pragma unroll
      for (int r = 0; r < 4; r++){
        int row = mBase + wr * 64 + mt * 16 + quad * 4 + r;
        int col = nBase + wc * (BN / 2) + nt * 16 + r16;
        C[(size_t)row * Nc + col] = f2bf(acc[mt][nt][r]);
      }
    }
  }
}

// ---------------- alpha for H=4: alpha_s/d[N,4] from h[N,256] bf16 ----------------

__global__ __launch_bounds__(256) void alpha4_k(const unsigned short* __restrict__ hb,
                                                const float* __restrict__ a_src,
                                                const float* __restrict__ a_dst,
                                                float* __restrict__ as_arr,
                                                float* __restrict__ ad_arr){
  __shared__ float s_lds[256], d_lds[256];
  int tid = threadIdx.x;
  s_lds[tid] = a_src[tid];
  d_lds[tid] = a_dst[tid];
  __syncthreads();
  int node = blockIdx.x * 16 + (tid >> 4);
  int q = tid & 15;
  int head = q >> 2;
  const short8* p = (const short8*)(hb + (size_t)node * 256 + q * 16);
  float ss = 0.f, sd = 0.f;
  #pragma unroll
  for (int b = 0; b < 2; b++){
    short8 v = p[b];
    #pragma unroll
    for (int j = 0; j < 8; j++){
      int cih = ((q & 3) * 16) + b * 8 + j;
      float f = bf2f((unsigned short)v[j]);
      ss += f * s_lds[head * 64 + cih];
      sd += f * d_lds[head * 64 + cih];
    }
  }
  ss += __shfl_xor(ss, 1, 64); ss += __shfl_xor(ss, 2, 64);
  sd += __shfl_xor(sd, 1, 64); sd += __shfl_xor(sd, 2, 64);
  if ((q & 3) == 0){ as_arr[node * 4 + head] = ss; ad_arr[node * 4 + head] = sd; }
}

// ---------------- alpha for H=1: alpha_s/d[N] from h[N,64] bf16 ----------------

__global__ __launch_bounds__(256) void alpha1_k(const unsigned short* __restrict__ hb,
                                                const float* __restrict__ a_src,
                                                const float* __restrict__ a_dst,
                                                float* __restrict__ as_arr,
                                                float* __restrict__ ad_arr){
  __shared__ float s_lds[64], d_lds[64];
  int tid = threadIdx.x;
  if (tid < 64){ s_lds[tid] = a_src[tid]; d_lds[tid] = a_dst[tid]; }
  __syncthreads();
  int node = blockIdx.x * 16 + (tid >> 4);
  int q = tid & 15;
  short4_t v = *(const short4_t*)(hb + (size_t)node * 64 + q * 4);
  float ss = 0.f, sd = 0.f;
  #pragma unroll
  for (int j = 0; j < 4; j++){
    float f = bf2f((unsigned short)v[j]);
    ss += f * s_lds[q * 4 + j];
    sd += f * d_lds[q * 4 + j];
  }
  ss += __shfl_xor(ss, 1, 64); ss += __shfl_xor(ss, 2, 64);
  ss += __shfl_xor(ss, 4, 64); ss += __shfl_xor(ss, 8, 64);
  sd += __shfl_xor(sd, 1, 64); sd += __shfl_xor(sd, 2, 64);
  sd += __shfl_xor(sd, 4, 64); sd += __shfl_xor(sd, 8, 64);
  if (q == 0){ as_arr[node] = ss; ad_arr[node] = sd; }
}

// ---------------- conv1 aggregation (table-based h1), fused softmax, +b1, ELU ----------------

__global__ __launch_bounds__(256) void agg1_k(const int* __restrict__ x,
                                              const float* __restrict__ T1,
                                              const float* __restrict__ as_tab,
                                              const float* __restrict__ ad_tab,
                                              const int* __restrict__ row_ptr,
                                              const int* __restrict__ sorted_src,
                                              const float* __restrict__ bias,
                                              unsigned short* __restrict__ outb){
  __shared__ float t_lds[1280];
  __shared__ float as_lds[20], ad_lds[20], b_lds[256];
  int tid = threadIdx.x;
  for (int i = tid; i < 1280; i += 256) t_lds[i] = T1[i];
  if (tid < 20){ as_lds[tid] = as_tab[tid]; ad_lds[tid] = ad_tab[tid]; }
  b_lds[tid] = bias[tid];
  __syncthreads();
  int w = tid >> 6, l = tid & 63;
  int d = blockIdx.x * 4 + w;
  int hl = l & 31, half = l >> 5;
  int head = hl >> 3;
  int start = row_ptr[d], end = row_ptr[d + 1];
  float a_d = ad_lds[x[d] * 4 + head];
  float acc[8] = {0.f,0.f,0.f,0.f,0.f,0.f,0.f,0.f};
  float den = 0.f;
  for (int e = start + half; e < end; e += 2){
    int s = sorted_src[e];
    int xs = x[s];
    float wg = __expf(lrelu(as_lds[xs * 4 + head] + a_d));
    den += wg;
    const float* row = &t_lds[xs * 256 + hl * 8];
    #pragma unroll
    for (int j = 0; j < 8; j++) acc[j] += wg * row[j];
  }
  #pragma unroll
  for (int j = 0; j < 8; j++) acc[j] += __shfl_xor(acc[j], 32, 64);
  den += __shfl_xor(den, 32, 64);
  if (half == 0){
    float inv = 1.f / (den + 1e-16f);
    short8 ov;
    #pragma unroll
    for (int j = 0; j < 8; j++){
      float v = eluf(acc[j] * inv + b_lds[hl * 8 + j]);
      ov[j] = (short)f2bf(v);
    }
    *(short8*)(outb + (size_t)d * 256 + hl * 8) = ov;
  }
}

// ---------------- conv2 aggregation (h[N,256] bf16), fused softmax, +b2, ELU ----------------

__global__ __launch_bounds__(256) void agg4_k(const unsigned short* __restrict__ hb,
                                              const float* __restrict__ as_arr,
                                              const float* __restrict__ ad_arr,
                                              const int* __restrict__ row_ptr,
                                              const int* __restrict__ sorted_src,
                                              const float* __restrict__ bias,
                                              unsigned short* __restrict__ outb){
  __shared__ float b_lds[256];
  int tid = threadIdx.x;
  b_lds[tid] = bias[tid];
  __syncthreads();
  int w = tid >> 6, l = tid & 63;
  int d = blockIdx.x * 4 + w;
  int hl = l & 31, half = l >> 5;
  int head = hl >> 3;
  int start = row_ptr[d], end = row_ptr[d + 1];
  float a_d = ad_arr[d * 4 + head];
  float acc[8] = {0.f,0.f,0.f,0.f,0.f,0.f,0.f,0.f};
  float den = 0.f;
  for (int e = start + half; e < end; e += 2){
    int s = sorted_src[e];
    float wg = __expf(lrelu(as_arr[s * 4 + head] + a_d));
    den += wg;
    short8 v = *(const short8*)(hb + (size_t)s * 256 + hl * 8);
    #pragma unroll
    for (int j = 0; j < 8; j++) acc[j] += wg * bf2f((unsigned short)v[j]);
  }
  #pragma unroll
  for (int j = 0; j < 8; j++) acc[j] += __shfl_xor(acc[j], 32, 64);
  den += __shfl_xor(den, 32, 64);
  if (half == 0){
    float inv = 1.f / (den + 1e-16f);
    short8 ov;
    #pragma unroll
    for (int j = 0; j < 8; j++){
      float v = eluf(acc[j] * inv + b_lds[hl * 8 + j]);
      ov[j] = (short)f2bf(v);
    }
    *(short8*)(outb + (size_t)d * 256 + hl * 8) = ov;
  }
}

// ---------------- conv3 aggregation (h[N,64] bf16, H=1), +b3, ELU ----------------

__global__ __launch_bounds__(256) void agg3_k(const unsigned short* __restrict__ hb,
                                              const float* __restrict__ as_arr,
                                              const float* __restrict__ ad_arr,
                                              const int* __restrict__ row_ptr,
                                              const int* __restrict__ sorted_src,
                                              const float* __restrict__ bias,
                                              unsigned short* __restrict__ outb){
  __shared__ float b_lds[64];
  int tid = threadIdx.x;
  if (tid < 64) b_lds[tid] = bias[tid];
  __syncthreads();
  int w = tid >> 6, l = tid & 63;
  int d = blockIdx.x * 4 + w;
  int q = l & 15, grp = l >> 4;
  int start = row_ptr[d], end = row_ptr[d + 1];
  float a_d = ad_arr[d];
  float acc[4] = {0.f,0.f,0.f,0.f};
  float den = 0.f;
  for (int e = start + grp; e < end; e += 4){
    int s = sorted_src[e];
    float wg = __expf(lrelu(as_arr[s] + a_d));
    den += wg;
    short4_t v = *(const short4_t*)(hb + (size_t)s * 64 + q * 4);
    #pragma unroll
    for (int j = 0; j < 4; j++) acc[j] += wg * bf2f((unsigned short)v[j]);
  }
  #pragma unroll
  for (int j = 0; j < 4; j++){
    acc[j] += __shfl_xor(acc[j], 16, 64);
    acc[j] += __shfl_xor(acc[j], 32, 64);
  }
  den += __shfl_xor(den, 16, 64);
  den += __shfl_xor(den, 32, 64);
  if (l < 16){
    float inv = 1.f / (den + 1e-16f);
    short4_t ov;
    #pragma unroll
    for (int j = 0; j < 4; j++){
      float v = eluf(acc[j] * inv + b_lds[q * 4 + j]);
      ov[j] = (short)f2bf(v);
    }
    *(short4_t*)(outb + (size_t)d * 64 + q * 4) = ov;
  }
}

// ---------------- final FC: out[N,5] = h[N,64] @ fc_w + fc_b ----------------

__global__ __launch_bounds__(256) void fc_k(const unsigned short* __restrict__ hb,
                                            const float* __restrict__ fcw,
                                            const float* __restrict__ fcb,
                                            float* __restrict__ out){
  __shared__ float w_lds[320];
  __shared__ float b_lds[5];
  int tid = threadIdx.x;
  for (int i = tid; i < 320; i += 256) w_lds[i] = fcw[i];
  if (tid < 5) b_lds[tid] = fcb[tid];
  __syncthreads();
  int n = blockIdx.x * 256 + tid;
  const short8* p = (const short8*)(hb + (size_t)n * 64);
  float acc[5];
  #pragma unroll
  for (int j = 0; j < 5; j++) acc[j] = b_lds[j];
  #pragma unroll
  for (int b = 0; b < 8; b++){
    short8 v = p[b];
    #pragma unroll
    for (int j8 = 0; j8 < 8; j8++){
      float f = bf2f((unsigned short)v[j8]);
      int k = b * 8 + j8;
      #pragma unroll
      for (int j = 0; j < 5; j++) acc[j] += f * w_lds[k * 5 + j];
    }
  }
  #pragma unroll
  for (int j = 0; j < 5; j++) out[(size_t)n * 5 + j] = acc[j];
}

// ---------------- host launch ----------------

extern "C" void kernel_launch(void* const* d_in, const int* in_sizes, int n_in,
                              void* d_out, int out_size, void* d_ws, size_t ws_size,
                              hipStream_t stream){
  const int*   x    = (const int*)d_in[0];
  const int*   ei   = (const int*)d_in[1];
  const float* emb  = (const float*)d_in[2];
  const float* W1   = (const float*)d_in[3];
  const float* a1s  = (const float*)d_in[4];
  const float* a1d  = (const float*)d_in[5];
  const float* b1   = (const float*)d_in[6];
  const float* W2   = (const float*)d_in[7];
  const float* a2s  = (const float*)d_in[8];
  const float* a2d  = (const float*)d_in[9];
  const float* b2   = (const float*)d_in[10];
  const float* W3   = (const float*)d_in[11];
  const float* a3s  = (const float*)d_in[12];
  const float* a3d  = (const float*)d_in[13];
  const float* b3   = (const float*)d_in[14];
  const float* fcw  = (const float*)d_in[15];
  const float* fcb  = (const float*)d_in[16];
  float* out = (float*)d_out;

  const int N = in_sizes[0];
  const int E = in_sizes[1] / 2;
  const int Etot = E + N;
  const int nb = (N + 1023) / 1024;   // scan blocks

  // workspace partition (256B aligned)
  char* base = (char*)d_ws;
  size_t off = 0;
  auto alloc = [&](size_t bytes) -> void* {
    void* p = base + off;
    off += (bytes + 255) & ~(size_t)255;
    return p;
  };
  unsigned short* bufA    = (unsigned short*)alloc((size_t)N * 256 * 2);
  unsigned short* bufB    = (unsigned short*)alloc((size_t)N * 256 * 2);
  float* alpha_s          = (float*)alloc((size_t)N * 4 * 4);
  float* alpha_d          = (float*)alloc((size_t)N * 4 * 4);
  int* counts             = (int*)alloc((size_t)N * 4);
  int* row_ptr            = (int*)alloc((size_t)(N + 1) * 4);
  int* cursor             = (int*)alloc((size_t)N * 4);
  int* sorted_src         = (int*)alloc((size_t)Etot * 4);
  int* bsum               = (int*)alloc((size_t)(nb + 1) * 4);
  float* T1               = (float*)alloc(5 * 256 * 4);
  float* as_tab           = (float*)alloc(20 * 4);
  float* ad_tab           = (float*)alloc(20 * 4);
  unsigned short* Wp2     = (unsigned short*)alloc(256 * 256 * 2);
  unsigned short* Wp3     = (unsigned short*)alloc(64 * 256 * 2);

  // ---- build CSR by dst (shared by all 3 convs) ----
  hipMemsetAsync(counts, 0, (size_t)N * 4, stream);
  hist_k<<<1024, 256, 0, stream>>>(ei, E, N, counts);
  scan_blk_k<<<nb, 1024, 0, stream>>>(counts, row_ptr, bsum, N);
  scan_top_k<<<1, 1024, 0, stream>>>(bsum, nb);
  scan_add_k<<<nb, 1024, 0, stream>>>(bsum, row_ptr, cursor, N, nb);
  scatter_k<<<1024, 256, 0, stream>>>(ei, E, N, cursor, sorted_src);

  // ---- prep: conv1 tables, packed bf16 weights ----
  table1_k<<<1, 256, 0, stream>>>(emb, W1, a1s, a1d, T1, as_tab, ad_tab);
  pack_k<<<(256 * 256 + 255) / 256, 256, 0, stream>>>(W2, Wp2, 256, 256);
  pack_k<<<(256 * 64 + 255) / 256, 256, 0, stream>>>(W3, Wp3, 256, 64);

  // ---- conv1: table-gather aggregation -> bufB [N,256] bf16 ----
  agg1_k<<<N / 4, 256, 0, stream>>>(x, T1, as_tab, ad_tab, row_ptr, sorted_src, b1, bufB);

  // ---- conv2 ----
  gemm_lds_k<128><<<dim3(N / 128, 2), 256, 0, stream>>>(bufB, Wp2, bufA, 256);
  alpha4_k<<<N / 16, 256, 0, stream>>>(bufA, a2s, a2d, alpha_s, alpha_d);
  agg4_k<<<N / 4, 256, 0, stream>>>(bufA, alpha_s, alpha_d, row_ptr, sorted_src, b2, bufB);

  // ---- conv3 ----
  gemm_lds_k<64><<<dim3(N / 128, 1), 256, 0, stream>>>(bufB, Wp3, bufA, 64);
  alpha1_k<<<N / 16, 256, 0, stream>>>(bufA, a3s, a3d, alpha_s, alpha_d);
  agg3_k<<<N / 4, 256, 0, stream>>>(bufA, alpha_s, alpha_d, row_ptr, sorted_src, b3, bufB);

  // ---- final FC -> d_out [N,5] f32 ----
  fc_k<<<N / 256, 256, 0, stream>>>(bufB, fcw, fcb, out);
}